// Round 11
// baseline (213.698 us; speedup 1.0000x reference)
//
#include <hip/hip_runtime.h>
#include <hip/hip_fp16.h>
#include <stdint.h>

typedef int v4i  __attribute__((ext_vector_type(4)));
typedef int v16i __attribute__((ext_vector_type(16)));

#define GLOAD_LDS16(g, l) __builtin_amdgcn_global_load_lds(                  \
    (const __attribute__((address_space(1))) void*)(g),                      \
    (__attribute__((address_space(3))) void*)(l), 16, 0, 0)

// workspace layout (bytes)
#define XQ_OFF 0u
#define XS_OFF 33554432u              // M*K int8
#define W8_OFF 33570816u              // + M*2 fp16 scales

// ---------------------------------------------------------------------------
// Self-classification of input delivery: x widened fp16->f32 has low 13
// mantissa bits zero; w widened int8->int32 has every word in [-128,127].
// ---------------------------------------------------------------------------
__device__ inline bool x_is_f32(const void* xin) {
  const uint32_t* xw = (const uint32_t*)xin;
  bool ok = true;
  #pragma unroll
  for (int i = 0; i < 16; ++i) ok &= ((xw[i] & 0x1FFFu) == 0u);
  return ok;
}
__device__ inline bool w_is_i32(const void* win) {
  const int* wi = (const int*)win;
  bool ok = true;
  #pragma unroll
  for (int i = 0; i < 16; ++i) ok &= (wi[i] >= -128 && wi[i] <= 127);
  return ok;
}

// ---------------------------------------------------------------------------
// Fused prologue: blocks [0, M) do per-token int8 quant of x; blocks
// [M, M+RW_BLOCKS) repack w into contiguous int8. Both memory-bound on
// disjoint streams -> run concurrently at full HBM BW, one launch.
// ---------------------------------------------------------------------------
#define RW_BLOCKS 1024

__global__ __launch_bounds__(256) void prologue(
    const void* __restrict__ xin, const void* __restrict__ win,
    int8_t* __restrict__ xq, __half* __restrict__ xs,
    int8_t* __restrict__ w8, int K, int M, int wtotal)
{
  const int tid = threadIdx.x;

  if (blockIdx.x >= (unsigned)M) {
    // ---- repack w ----
    const bool as32 = w_is_i32(win);
    const int bid  = blockIdx.x - M;
    const int gtid = bid * 256 + tid;
    const int nthr = RW_BLOCKS * 256;
    if (as32) {
      const int4* w4 = (const int4*)win;
      uint32_t* dst = (uint32_t*)w8;
      const int n4 = wtotal >> 2;
      for (int i = gtid; i < n4; i += nthr) {
        int4 v = w4[i];
        dst[i] = (uint32_t)(v.x & 255) | ((uint32_t)(v.y & 255) << 8) |
                 ((uint32_t)(v.z & 255) << 16) | ((uint32_t)(v.w & 255) << 24);
      }
    } else {
      const uint4* src = (const uint4*)win;
      uint4* dst = (uint4*)w8;
      const int n16 = wtotal >> 4;
      for (int i = gtid; i < n16; i += nthr) dst[i] = src[i];
    }
    return;
  }

  // ---- quant row ----
  const bool xf32 = x_is_f32(xin);
  const int row  = blockIdx.x;
  const int lane = tid & 63;
  const int wv   = tid >> 6;
  const size_t base = (size_t)row * (size_t)K;
  __shared__ float wmax[4];

  if (xf32 && K == 4096) {
    const float4* x4 = (const float4*)((const float*)xin + base);
    float4 v[4];
    #pragma unroll
    for (int i = 0; i < 4; ++i) v[i] = x4[i * 256 + tid];
    float mx = 0.0f;
    #pragma unroll
    for (int i = 0; i < 4; ++i)
      mx = fmaxf(mx, fmaxf(fmaxf(fabsf(v[i].x), fabsf(v[i].y)),
                           fmaxf(fabsf(v[i].z), fabsf(v[i].w))));
    #pragma unroll
    for (int off = 32; off; off >>= 1) mx = fmaxf(mx, __shfl_xor(mx, off, 64));
    if (lane == 0) wmax[wv] = mx;
    __syncthreads();
    const float scale =
        fmaxf(fmaxf(wmax[0], wmax[1]), fmaxf(wmax[2], wmax[3])) / 127.0f;
    if (tid == 0) xs[row] = __float2half(scale);
    uint32_t* q = (uint32_t*)(xq + base);
    #pragma unroll
    for (int i = 0; i < 4; ++i) {
      float f[4] = {v[i].x, v[i].y, v[i].z, v[i].w};
      uint32_t p = 0;
      #pragma unroll
      for (int j = 0; j < 4; ++j) {
        float r = fminf(127.0f, fmaxf(-128.0f, rintf(f[j] / scale)));
        p |= ((uint32_t)((int)r & 255)) << (8 * j);
      }
      q[i * 256 + tid] = p;
    }
    return;
  }

  // generic two-pass fallback
  float mx = 0.0f;
  if (xf32) {
    const float* x = (const float*)xin + base;
    for (int k = tid * 4; k < K; k += 256 * 4) {
      float4 v = *(const float4*)(x + k);
      mx = fmaxf(mx, fmaxf(fmaxf(fabsf(v.x), fabsf(v.y)),
                           fmaxf(fabsf(v.z), fabsf(v.w))));
    }
  } else {
    const __half* x = (const __half*)xin + base;
    for (int k = tid * 8; k < K; k += 256 * 8) {
      uint4 u = *(const uint4*)(x + k);
      const __half* hp = (const __half*)&u;
      #pragma unroll
      for (int j = 0; j < 8; ++j) mx = fmaxf(mx, fabsf(__half2float(hp[j])));
    }
  }
  #pragma unroll
  for (int off = 32; off; off >>= 1) mx = fmaxf(mx, __shfl_xor(mx, off, 64));
  if (lane == 0) wmax[wv] = mx;
  __syncthreads();
  const float scale =
      fmaxf(fmaxf(wmax[0], wmax[1]), fmaxf(wmax[2], wmax[3])) / 127.0f;
  if (tid == 0) xs[row] = __float2half(scale);

  for (int k = tid * 8; k < K; k += 256 * 8) {
    float f[8];
    if (xf32) {
      const float* x = (const float*)xin + base;
      float4 a = *(const float4*)(x + k);
      float4 b = *(const float4*)(x + k + 4);
      f[0]=a.x; f[1]=a.y; f[2]=a.z; f[3]=a.w; f[4]=b.x; f[5]=b.y; f[6]=b.z; f[7]=b.w;
    } else {
      const __half* x = (const __half*)xin + base;
      uint4 u = *(const uint4*)(x + k);
      const __half* hp = (const __half*)&u;
      #pragma unroll
      for (int j = 0; j < 8; ++j) f[j] = __half2float(hp[j]);
    }
    uint32_t p0 = 0, p1 = 0;
    #pragma unroll
    for (int j = 0; j < 4; ++j) {
      float r = fminf(127.0f, fmaxf(-128.0f, rintf(f[j] / scale)));
      p0 |= ((uint32_t)((int)r & 255)) << (8 * j);
    }
    #pragma unroll
    for (int j = 0; j < 4; ++j) {
      float r = fminf(127.0f, fmaxf(-128.0f, rintf(f[4 + j] / scale)));
      p1 |= ((uint32_t)((int)r & 255)) << (8 * j);
    }
    uint2 st; st.x = p0; st.y = p1;
    *(uint2*)(xq + base + k) = st;
  }
}

// ---------------------------------------------------------------------------
// int8 GEMM, 256x256 tile, BK=128, 8 waves (2Mx4N), mfma_i32_32x32x32_i8
// (4404 TOPS ceiling, half the MFMA issue count of 16x16), double-buffered
// LDS (128KiB), one barrier per K-tile, per-k-step register pipelining with
// counted lgkmcnt(6), counted vmcnt (stage early, drain at tile end).
// Fragment layouts: A/B row = lane&31, k-chunk = lane>>5 (analog of the
// verified 16x16 mapping); C/D col = lane&31, row = (reg&3)+8*(reg>>2)+
// 4*(lane>>5) [m74/m101]. Requires K % 128 == 0, K/128 >= 2, M,N % 256 == 0.
// ---------------------------------------------------------------------------
__global__ __launch_bounds__(512, 2) void gemm_w8a8(
    const int8_t* __restrict__ xq, const int8_t* __restrict__ wq,
    const __half* __restrict__ xs, const float* __restrict__ wscale,
    const float* __restrict__ mos, float* __restrict__ out,
    int M, int N, int K)
{
  __shared__ int8_t sA[2][256 * 128];   // 64 KiB
  __shared__ int8_t sB[2][256 * 128];   // 64 KiB

  const int tid  = threadIdx.x;
  const int lane = tid & 63;
  const int w    = tid >> 6;
  const int wr   = w >> 2;        // 0..1 -> 128 rows of C
  const int wc   = w & 3;         // 0..3 -> 64 cols of C
  const int l31  = lane & 31;
  const int hk   = lane >> 5;     // k-half: lanes<32 -> k 0..15, >=32 -> 16..31

  // XCD-aware swizzle (bijective: gridDim.x % 8 == 0 for our shapes)
  int L = blockIdx.x;
  const int nwg = gridDim.x;
  if ((nwg & 7) == 0) L = (L & 7) * (nwg >> 3) + (L >> 3);
  const int ntn = N >> 8;
  const int bn = (L % ntn) << 8;
  const int bm = (L / ntn) << 8;

  v16i acc[4][2];
  #pragma unroll
  for (int i = 0; i < 4; ++i)
    #pragma unroll
    for (int j = 0; j < 2; ++j)
      #pragma unroll
      for (int r = 0; r < 16; ++r) acc[i][j][r] = 0;

  // stage 256x128B tile; LDS slot (r,p) holds global chunk p ^ (r&7)
  auto stageA = [&](int kt, int buf) {
    const int k0 = kt << 7;
    #pragma unroll
    for (int i = 0; i < 4; ++i) {
      const int li = i * 512 + tid;
      const int r  = li >> 3;
      const int p  = li & 7;
      const int sc = p ^ (r & 7);
      GLOAD_LDS16(xq + (size_t)(bm + r) * K + k0 + (sc << 4),
                  &sA[buf][(i * 512 + (w << 6)) << 4]);
    }
  };
  auto stageB = [&](int kt, int buf) {
    const int k0 = kt << 7;
    #pragma unroll
    for (int i = 0; i < 4; ++i) {
      const int li = i * 512 + tid;
      const int r  = li >> 3;
      const int p  = li & 7;
      const int sc = p ^ (r & 7);
      GLOAD_LDS16(wq + (size_t)(bn + r) * K + k0 + (sc << 4),
                  &sB[buf][(i * 512 + (w << 6)) << 4]);
    }
  };

  // Per k-step ks (K=32 each): lane reads row, 16B at global chunk 2ks+hk.
  // LDS slot = (2ks+hk) ^ (row&7); row&7 == lane&7 (row bases are x32).
  // byte = row*128 + slot*16 ; ks advance = XOR (ks<<5) on the base.
  const int rowA0 = (wr << 7) + l31;
  const int aoffb = rowA0 * 128 + (((hk) ^ (lane & 7)) << 4);
  const int rowB0 = (wc << 6) + l31;
  const int boffb = rowB0 * 128 + (((hk) ^ (lane & 7)) << 4);

  const int nt = K >> 7;   // 32 for K=4096

  // prologue
  stageA(0, 0); stageB(0, 0);
  asm volatile("s_waitcnt vmcnt(0)" ::: "memory");
  __builtin_amdgcn_s_barrier();

#define READ_KS(AV, BV, KS)                                                  \
    _Pragma("unroll")                                                        \
    for (int mt = 0; mt < 4; ++mt)                                           \
      AV[mt] = *(const v4i*)(Ab + ((aoffb ^ ((KS) << 5)) + mt * 4096));      \
    _Pragma("unroll")                                                        \
    for (int nl = 0; nl < 2; ++nl)                                           \
      BV[nl] = *(const v4i*)(Bb + ((boffb ^ ((KS) << 5)) + nl * 4096));

#define MFMA_KS(AV, BV)                                                      \
    __builtin_amdgcn_s_setprio(1);                                           \
    _Pragma("unroll")                                                        \
    for (int mt = 0; mt < 4; ++mt)                                           \
      _Pragma("unroll")                                                      \
      for (int nl = 0; nl < 2; ++nl)                                         \
        acc[mt][nl] = __builtin_amdgcn_mfma_i32_32x32x32_i8(                 \
            AV[mt], BV[nl], acc[mt][nl], 0, 0, 0);                           \
    __builtin_amdgcn_s_setprio(0);

  #pragma unroll 1
  for (int t = 0; t < nt; ++t) {
    const int buf = t & 1;
    const int8_t* Ab = sA[buf];
    const int8_t* Bb = sB[buf];
    const bool do_stage = (t + 1 < nt);
    v4i A0[4], A1[4], B0[2], B1[2];

    READ_KS(A0, B0, 0)                       // 6 reads (gate)
    if (do_stage) stageA(t + 1, buf ^ 1);    // 4 gloads, early
    READ_KS(A1, B1, 1)                       // 6 reads under ks0 MFMA
    asm volatile("s_waitcnt lgkmcnt(6)" ::: "memory");   // ks0 landed
    MFMA_KS(A0, B0)

    if (do_stage) stageB(t + 1, buf ^ 1);    // 4 gloads
    READ_KS(A0, B0, 2)                       // 6 reads under ks1 MFMA
    asm volatile("s_waitcnt lgkmcnt(6)" ::: "memory");   // ks1 landed
    MFMA_KS(A1, B1)

    READ_KS(A1, B1, 3)                       // 6 reads under ks2 MFMA
    asm volatile("s_waitcnt lgkmcnt(6)" ::: "memory");   // ks2 landed
    MFMA_KS(A0, B0)

    asm volatile("s_waitcnt lgkmcnt(0)" ::: "memory");   // ks3 landed
    MFMA_KS(A1, B1)

    // stage(t+1) must be fully resident before next iter's reads
    asm volatile("s_waitcnt vmcnt(0)" ::: "memory");
    __builtin_amdgcn_s_barrier();
  }

#undef READ_KS
#undef MFMA_KS

  // epilogue: out = (float(half(acc*s_out)) * wscale[n]) * float(half_scale[m])
  // C/D: col = lane&31, row = (reg&3) + 8*(reg>>2) + 4*(lane>>5)
  const float s_out = mos[0];
  #pragma unroll
  for (int nl = 0; nl < 2; ++nl) {
    const int n_g = bn + (wc << 6) + nl * 32 + l31;
    const float wsc = wscale[n_g];
    #pragma unroll
    for (int mt = 0; mt < 4; ++mt) {
      #pragma unroll
      for (int r = 0; r < 16; ++r) {
        const int m_g = bm + (wr << 7) + mt * 32 + (r & 3) + 8 * (r >> 2) + 4 * hk;
        const float y = __half2float(__float2half((float)acc[mt][nl][r] * s_out));
        out[(size_t)m_g * N + n_g] = (y * wsc) * __half2float(xs[m_g]);
      }
    }
  }
}

// ---------------------------------------------------------------------------
extern "C" void kernel_launch(void* const* d_in, const int* in_sizes, int n_in,
                              void* d_out, int out_size, void* d_ws, size_t ws_size,
                              hipStream_t stream) {
  const void*  x      = d_in[0];
  const void*  win    = d_in[1];
  const float* wscale = (const float*)d_in[2];
  const float* mos    = (const float*)d_in[3];
  float*       out    = (float*)d_out;

  const int N = in_sizes[2];            // 4096
  const int K = in_sizes[1] / N;        // 4096
  const int M = in_sizes[0] / K;        // 8192

  int8_t* xq = (int8_t*)d_ws + XQ_OFF;
  __half* xs = (__half*)((char*)d_ws + XS_OFF);
  int8_t* w8 = (int8_t*)d_ws + W8_OFF;

  prologue<<<M + RW_BLOCKS, 256, 0, stream>>>(x, win, xq, xs, w8, K, M, N * K);

  gemm_w8a8<<<dim3((M >> 8) * (N >> 8)), 512, 0, stream>>>(
      xq, w8, xs, wscale, mos, out, M, N, K);
}

// Round 12
// 187.686 us; speedup vs baseline: 1.1386x; 1.1386x over previous
//
#include <hip/hip_runtime.h>
#include <hip/hip_fp16.h>
#include <stdint.h>

typedef int v4i __attribute__((ext_vector_type(4)));

#define GLOAD_LDS16(g, l) __builtin_amdgcn_global_load_lds(                  \
    (const __attribute__((address_space(1))) void*)(g),                      \
    (__attribute__((address_space(3))) void*)(l), 16, 0, 0)

// workspace layout (bytes)
#define XQ_OFF 0u
#define XS_OFF 33554432u              // M*K int8
#define W8_OFF 33570816u              // + M*2 fp16 scales

// ---------------------------------------------------------------------------
// Self-classification of input delivery: x widened fp16->f32 has low 13
// mantissa bits zero; w widened int8->int32 has every word in [-128,127].
// ---------------------------------------------------------------------------
__device__ inline bool x_is_f32(const void* xin) {
  const uint32_t* xw = (const uint32_t*)xin;
  bool ok = true;
  #pragma unroll
  for (int i = 0; i < 16; ++i) ok &= ((xw[i] & 0x1FFFu) == 0u);
  return ok;
}
__device__ inline bool w_is_i32(const void* win) {
  const int* wi = (const int*)win;
  bool ok = true;
  #pragma unroll
  for (int i = 0; i < 16; ++i) ok &= (wi[i] >= -128 && wi[i] <= 127);
  return ok;
}

// ---------------------------------------------------------------------------
// Fused prologue: blocks [0, M) do per-token int8 quant of x; blocks
// [M, M+RW_BLOCKS) repack w into contiguous int8. Both memory-bound on
// disjoint streams -> run concurrently at full HBM BW, one launch.
// ---------------------------------------------------------------------------
#define RW_BLOCKS 1024

__global__ __launch_bounds__(256) void prologue(
    const void* __restrict__ xin, const void* __restrict__ win,
    int8_t* __restrict__ xq, __half* __restrict__ xs,
    int8_t* __restrict__ w8, int K, int M, int wtotal)
{
  const int tid = threadIdx.x;

  if (blockIdx.x >= (unsigned)M) {
    // ---- repack w ----
    const bool as32 = w_is_i32(win);
    const int bid  = blockIdx.x - M;
    const int gtid = bid * 256 + tid;
    const int nthr = RW_BLOCKS * 256;
    if (as32) {
      const int4* w4 = (const int4*)win;
      uint32_t* dst = (uint32_t*)w8;
      const int n4 = wtotal >> 2;
      for (int i = gtid; i < n4; i += nthr) {
        int4 v = w4[i];
        dst[i] = (uint32_t)(v.x & 255) | ((uint32_t)(v.y & 255) << 8) |
                 ((uint32_t)(v.z & 255) << 16) | ((uint32_t)(v.w & 255) << 24);
      }
    } else {
      const uint4* src = (const uint4*)win;
      uint4* dst = (uint4*)w8;
      const int n16 = wtotal >> 4;
      for (int i = gtid; i < n16; i += nthr) dst[i] = src[i];
    }
    return;
  }

  // ---- quant row ----
  const bool xf32 = x_is_f32(xin);
  const int row  = blockIdx.x;
  const int lane = tid & 63;
  const int wv   = tid >> 6;
  const size_t base = (size_t)row * (size_t)K;
  __shared__ float wmax[4];

  if (xf32 && K == 4096) {
    const float4* x4 = (const float4*)((const float*)xin + base);
    float4 v[4];
    #pragma unroll
    for (int i = 0; i < 4; ++i) v[i] = x4[i * 256 + tid];
    float mx = 0.0f;
    #pragma unroll
    for (int i = 0; i < 4; ++i)
      mx = fmaxf(mx, fmaxf(fmaxf(fabsf(v[i].x), fabsf(v[i].y)),
                           fmaxf(fabsf(v[i].z), fabsf(v[i].w))));
    #pragma unroll
    for (int off = 32; off; off >>= 1) mx = fmaxf(mx, __shfl_xor(mx, off, 64));
    if (lane == 0) wmax[wv] = mx;
    __syncthreads();
    const float scale =
        fmaxf(fmaxf(wmax[0], wmax[1]), fmaxf(wmax[2], wmax[3])) / 127.0f;
    if (tid == 0) xs[row] = __float2half(scale);
    uint32_t* q = (uint32_t*)(xq + base);
    #pragma unroll
    for (int i = 0; i < 4; ++i) {
      float f[4] = {v[i].x, v[i].y, v[i].z, v[i].w};
      uint32_t p = 0;
      #pragma unroll
      for (int j = 0; j < 4; ++j) {
        float r = fminf(127.0f, fmaxf(-128.0f, rintf(f[j] / scale)));
        p |= ((uint32_t)((int)r & 255)) << (8 * j);
      }
      q[i * 256 + tid] = p;
    }
    return;
  }

  // generic two-pass fallback
  float mx = 0.0f;
  if (xf32) {
    const float* x = (const float*)xin + base;
    for (int k = tid * 4; k < K; k += 256 * 4) {
      float4 v = *(const float4*)(x + k);
      mx = fmaxf(mx, fmaxf(fmaxf(fabsf(v.x), fabsf(v.y)),
                           fmaxf(fabsf(v.z), fabsf(v.w))));
    }
  } else {
    const __half* x = (const __half*)xin + base;
    for (int k = tid * 8; k < K; k += 256 * 8) {
      uint4 u = *(const uint4*)(x + k);
      const __half* hp = (const __half*)&u;
      #pragma unroll
      for (int j = 0; j < 8; ++j) mx = fmaxf(mx, fabsf(__half2float(hp[j])));
    }
  }
  #pragma unroll
  for (int off = 32; off; off >>= 1) mx = fmaxf(mx, __shfl_xor(mx, off, 64));
  if (lane == 0) wmax[wv] = mx;
  __syncthreads();
  const float scale =
      fmaxf(fmaxf(wmax[0], wmax[1]), fmaxf(wmax[2], wmax[3])) / 127.0f;
  if (tid == 0) xs[row] = __float2half(scale);

  for (int k = tid * 8; k < K; k += 256 * 8) {
    float f[8];
    if (xf32) {
      const float* x = (const float*)xin + base;
      float4 a = *(const float4*)(x + k);
      float4 b = *(const float4*)(x + k + 4);
      f[0]=a.x; f[1]=a.y; f[2]=a.z; f[3]=a.w; f[4]=b.x; f[5]=b.y; f[6]=b.z; f[7]=b.w;
    } else {
      const __half* x = (const __half*)xin + base;
      uint4 u = *(const uint4*)(x + k);
      const __half* hp = (const __half*)&u;
      #pragma unroll
      for (int j = 0; j < 8; ++j) f[j] = __half2float(hp[j]);
    }
    uint32_t p0 = 0, p1 = 0;
    #pragma unroll
    for (int j = 0; j < 4; ++j) {
      float r = fminf(127.0f, fmaxf(-128.0f, rintf(f[j] / scale)));
      p0 |= ((uint32_t)((int)r & 255)) << (8 * j);
    }
    #pragma unroll
    for (int j = 0; j < 4; ++j) {
      float r = fminf(127.0f, fmaxf(-128.0f, rintf(f[4 + j] / scale)));
      p1 |= ((uint32_t)((int)r & 255)) << (8 * j);
    }
    uint2 st; st.x = p0; st.y = p1;
    *(uint2*)(xq + base + k) = st;
  }
}

// ---------------------------------------------------------------------------
// int8 GEMM (round-10 verified structure): 256x256 tile, BK=128, 8 waves
// (2Mx4N), mfma_i32_16x16x64_i8, double-buffered LDS (128KiB), one barrier
// per K-tile, register-pipelined fragments with counted lgkmcnt, counted
// vmcnt (stage issued early, drained at tile end). Swizzle: chunk ^= (row&7)
// over 8 16B-chunks per 128B row. K % 128 == 0, K/128 >= 2, M,N % 256 == 0.
// ---------------------------------------------------------------------------
__global__ __launch_bounds__(512, 2) void gemm_w8a8(
    const int8_t* __restrict__ xq, const int8_t* __restrict__ wq,
    const __half* __restrict__ xs, const float* __restrict__ wscale,
    const float* __restrict__ mos, float* __restrict__ out,
    int M, int N, int K)
{
  __shared__ int8_t sA[2][256 * 128];   // 64 KiB
  __shared__ int8_t sB[2][256 * 128];   // 64 KiB

  const int tid  = threadIdx.x;
  const int lane = tid & 63;
  const int w    = tid >> 6;
  const int wr   = w >> 2;        // 0..1 -> 128 rows of C
  const int wc   = w & 3;         // 0..3 -> 64 cols of C
  const int lr   = lane & 15;
  const int lk   = lane >> 4;

  // XCD-aware swizzle (bijective: gridDim.x % 8 == 0 for our shapes)
  int L = blockIdx.x;
  const int nwg = gridDim.x;
  if ((nwg & 7) == 0) L = (L & 7) * (nwg >> 3) + (L >> 3);
  const int ntn = N >> 8;
  const int bn = (L % ntn) << 8;
  const int bm = (L / ntn) << 8;

  v4i acc[8][4];
  #pragma unroll
  for (int i = 0; i < 8; ++i)
    #pragma unroll
    for (int j = 0; j < 4; ++j) {
      v4i z = {0, 0, 0, 0};
      acc[i][j] = z;
    }

  // stage 256x128B tile; LDS slot (r,p) holds global chunk p ^ (r&7)
  auto stageA = [&](int kt, int buf) {
    const int k0 = kt << 7;
    #pragma unroll
    for (int i = 0; i < 4; ++i) {
      const int li = i * 512 + tid;
      const int r  = li >> 3;
      const int p  = li & 7;
      const int sc = p ^ (r & 7);
      GLOAD_LDS16(xq + (size_t)(bm + r) * K + k0 + (sc << 4),
                  &sA[buf][(i * 512 + (w << 6)) << 4]);
    }
  };
  auto stageB = [&](int kt, int buf) {
    const int k0 = kt << 7;
    #pragma unroll
    for (int i = 0; i < 4; ++i) {
      const int li = i * 512 + tid;
      const int r  = li >> 3;
      const int p  = li & 7;
      const int sc = p ^ (r & 7);
      GLOAD_LDS16(wq + (size_t)(bn + r) * K + k0 + (sc << 4),
                  &sB[buf][(i * 512 + (w << 6)) << 4]);
    }
  };

  // swizzled ds_read byte offsets (kk=0); kk=1 base = kk=0 base XOR 64.
  // row&7 == lr&7 for all fragment rows (row-base offsets are x16).
  const int rowA0 = (wr << 7) + lr;
  const int aoff0 = rowA0 * 128 + ((lk ^ (lr & 7)) << 4);
  const int aoff1 = aoff0 ^ 64;
  const int rowB0 = (wc << 6) + lr;
  const int boff0 = rowB0 * 128 + ((lk ^ (lr & 7)) << 4);
  const int boff1 = boff0 ^ 64;

  const int nt = K >> 7;   // 32 for K=4096

  // prologue
  stageA(0, 0); stageB(0, 0);
  asm volatile("s_waitcnt vmcnt(0)" ::: "memory");
  __builtin_amdgcn_s_barrier();

  #pragma unroll 1
  for (int t = 0; t < nt; ++t) {
    const int buf = t & 1;
    const int8_t* Ab = sA[buf];
    const int8_t* Bb = sB[buf];
    const bool do_stage = (t + 1 < nt);
    v4i a00[4], a10[4], a01[4], a11[4], b0[4], b1[4];

    // gate burst: kk=0 h0 A-frags + kk=0 B-frags (8 reads)
    #pragma unroll
    for (int j = 0; j < 4; ++j) a00[j] = *(const v4i*)(Ab + aoff0 + j * 2048);
    #pragma unroll
    for (int j = 0; j < 4; ++j) b0[j]  = *(const v4i*)(Bb + boff0 + j * 2048);

    if (do_stage) stageA(t + 1, buf ^ 1);        // 4 gloads, ~2400cyc early

    asm volatile("s_waitcnt lgkmcnt(0)" ::: "memory");
    __builtin_amdgcn_s_setprio(1);
    #pragma unroll
    for (int j = 0; j < 4; ++j)
      #pragma unroll
      for (int ni = 0; ni < 4; ++ni)
        acc[j][ni] = __builtin_amdgcn_mfma_i32_16x16x64_i8(
            a00[j], b0[ni], acc[j][ni], 0, 0, 0);
    __builtin_amdgcn_s_setprio(0);

    // under-cover burst: h1/k0 A, k1 B, h0/k1 A (12 reads, in this order)
    #pragma unroll
    for (int j = 0; j < 4; ++j) a10[j] = *(const v4i*)(Ab + aoff0 + 8192 + j * 2048);
    #pragma unroll
    for (int j = 0; j < 4; ++j) b1[j]  = *(const v4i*)(Bb + boff1 + j * 2048);
    #pragma unroll
    for (int j = 0; j < 4; ++j) a01[j] = *(const v4i*)(Ab + aoff1 + j * 2048);

    if (do_stage) stageB(t + 1, buf ^ 1);        // 4 gloads, ~1800cyc early

    asm volatile("s_waitcnt lgkmcnt(8)" ::: "memory");   // a10 landed
    __builtin_amdgcn_s_setprio(1);
    #pragma unroll
    for (int j = 0; j < 4; ++j)
      #pragma unroll
      for (int ni = 0; ni < 4; ++ni)
        acc[4 + j][ni] = __builtin_amdgcn_mfma_i32_16x16x64_i8(
            a10[j], b0[ni], acc[4 + j][ni], 0, 0, 0);
    __builtin_amdgcn_s_setprio(0);

    // last A burst (4 reads)
    #pragma unroll
    for (int j = 0; j < 4; ++j) a11[j] = *(const v4i*)(Ab + aoff1 + 8192 + j * 2048);

    asm volatile("s_waitcnt lgkmcnt(4)" ::: "memory");   // b1,a01 landed
    __builtin_amdgcn_s_setprio(1);
    #pragma unroll
    for (int j = 0; j < 4; ++j)
      #pragma unroll
      for (int ni = 0; ni < 4; ++ni)
        acc[j][ni] = __builtin_amdgcn_mfma_i32_16x16x64_i8(
            a01[j], b1[ni], acc[j][ni], 0, 0, 0);
    __builtin_amdgcn_s_setprio(0);

    asm volatile("s_waitcnt lgkmcnt(0)" ::: "memory");   // a11 landed
    __builtin_amdgcn_s_setprio(1);
    #pragma unroll
    for (int j = 0; j < 4; ++j)
      #pragma unroll
      for (int ni = 0; ni < 4; ++ni)
        acc[4 + j][ni] = __builtin_amdgcn_mfma_i32_16x16x64_i8(
            a11[j], b1[ni], acc[4 + j][ni], 0, 0, 0);
    __builtin_amdgcn_s_setprio(0);

    // stage(t+1) must be fully resident before next iter's reads
    asm volatile("s_waitcnt vmcnt(0)" ::: "memory");
    __builtin_amdgcn_s_barrier();
  }

  // epilogue: out = (float(half(acc*s_out)) * wscale[n]) * float(half_scale[m])
  const float s_out = mos[0];
  #pragma unroll
  for (int ni = 0; ni < 4; ++ni) {
    const int n_g = bn + (wc << 6) + ni * 16 + lr;
    const float wsc = wscale[n_g];
    #pragma unroll
    for (int mi = 0; mi < 8; ++mi) {
      #pragma unroll
      for (int j = 0; j < 4; ++j) {
        const int m_g = bm + (wr << 7) + mi * 16 + lk * 4 + j;
        const float y = __half2float(__float2half((float)acc[mi][ni][j] * s_out));
        out[(size_t)m_g * N + n_g] = (y * wsc) * __half2float(xs[m_g]);
      }
    }
  }
}

// ---------------------------------------------------------------------------
extern "C" void kernel_launch(void* const* d_in, const int* in_sizes, int n_in,
                              void* d_out, int out_size, void* d_ws, size_t ws_size,
                              hipStream_t stream) {
  const void*  x      = d_in[0];
  const void*  win    = d_in[1];
  const float* wscale = (const float*)d_in[2];
  const float* mos    = (const float*)d_in[3];
  float*       out    = (float*)d_out;

  const int N = in_sizes[2];            // 4096
  const int K = in_sizes[1] / N;        // 4096
  const int M = in_sizes[0] / K;        // 8192

  int8_t* xq = (int8_t*)d_ws + XQ_OFF;
  __half* xs = (__half*)((char*)d_ws + XS_OFF);
  int8_t* w8 = (int8_t*)d_ws + W8_OFF;

  prologue<<<M + RW_BLOCKS, 256, 0, stream>>>(x, win, xq, xs, w8, K, M, N * K);

  gemm_w8a8<<<dim3((M >> 8) * (N >> 8)), 512, 0, stream>>>(
      xq, w8, xs, wscale, mos, out, M, N, K);
}